// Round 1
// baseline (286.829 us; speedup 1.0000x reference)
//
#include <hip/hip_runtime.h>

typedef __bf16 bf16x8 __attribute__((ext_vector_type(8)));
typedef __bf16 bf16x4 __attribute__((ext_vector_type(4)));
typedef float  f32x4  __attribute__((ext_vector_type(4)));

#define BM 128
#define BN 128
#define BK 32

// async global->LDS, 16B per lane. LDS dest must be wave-uniform base + lane*16.
__device__ __forceinline__ void gload_lds16(const __bf16* g, __bf16* l) {
  __builtin_amdgcn_global_load_lds(
      (const __attribute__((address_space(1))) void*)g,
      (__attribute__((address_space(3))) void*)l,
      16, 0, 0);
}

__global__ void cvt_f32_bf16(const float* __restrict__ s, __bf16* __restrict__ d, int n4) {
  int i = blockIdx.x * 256 + threadIdx.x;
  if (i < n4) {
    float4 v = ((const float4*)s)[i];
    bf16x4 o;
    o[0] = (__bf16)v.x; o[1] = (__bf16)v.y; o[2] = (__bf16)v.z; o[3] = (__bf16)v.w;
    ((bf16x4*)d)[i] = o;
  }
}

// C[m,n] = sum_k A[m,k]*B[n,k]  (both K-contiguous). 128x128 tile, BK=32,
// 4 waves each computing 64x64 via 4x4 mfma_f32_16x16x32_bf16.
// MODE 0: QKV epilogue (bias + split to Q, K row-major / V transposed, bf16)
// MODE 1: plain fp32 C store with ldc + batch stride (scores, PV)
template<int MODE>
__global__ __launch_bounds__(256, 2)
void gemm_bt(const __bf16* __restrict__ A, const __bf16* __restrict__ B,
             float* __restrict__ C,
             int lda, int ldb, int ldc, int K,
             long sA, long sB, long sC,
             const float* __restrict__ bq, const float* __restrict__ bk,
             const float* __restrict__ bv,
             __bf16* __restrict__ Qo, __bf16* __restrict__ Ko,
             __bf16* __restrict__ Vt)
{
  A += (long)blockIdx.z * sA;
  B += (long)blockIdx.z * sB;

  const int tid  = threadIdx.x;
  const int wave = tid >> 6;
  const int lane = tid & 63;
  const int quad = lane >> 4;
  const int l15  = lane & 15;
  const int bm0  = blockIdx.x * BM;
  const int bn0  = blockIdx.y * BN;
  const int wm   = (wave >> 1) * 64;
  const int wn   = (wave & 1) * 64;

  __shared__ __align__(16) __bf16 As[BM * BK];
  __shared__ __align__(16) __bf16 Bs[BN * BK];

  f32x4 acc[4][4];
#pragma unroll
  for (int i = 0; i < 4; ++i)
#pragma unroll
    for (int j = 0; j < 4; ++j)
      acc[i][j] = (f32x4){0.f, 0.f, 0.f, 0.f};

  // staging: 128x32 bf16 = 8KB per tile; 256 threads x 16B x 2 chunks
  const int l0 = tid * 8;          // chunk 0 linear element
  const int l1 = (256 + tid) * 8;  // chunk 1
  const int r0 = l0 >> 5, c0 = l0 & 31;
  const int r1 = l1 >> 5, c1 = l1 & 31;
  const __bf16* Ag0 = A + (size_t)(bm0 + r0) * lda + c0;
  const __bf16* Ag1 = A + (size_t)(bm0 + r1) * lda + c1;
  const __bf16* Bg0 = B + (size_t)(bn0 + r0) * ldb + c0;
  const __bf16* Bg1 = B + (size_t)(bn0 + r1) * ldb + c1;

  for (int k0 = 0; k0 < K; k0 += BK) {
    gload_lds16(Ag0 + k0, &As[l0]);
    gload_lds16(Ag1 + k0, &As[l1]);
    gload_lds16(Bg0 + k0, &Bs[l0]);
    gload_lds16(Bg1 + k0, &Bs[l1]);
    __syncthreads();  // waits vmcnt(0) for the LDS-bound loads

    bf16x8 af[4], bfv[4];
#pragma unroll
    for (int i = 0; i < 4; ++i)
      af[i] = *(const bf16x8*)&As[(wm + i * 16 + l15) * BK + quad * 8];
#pragma unroll
    for (int i = 0; i < 4; ++i)
      bfv[i] = *(const bf16x8*)&Bs[(wn + i * 16 + l15) * BK + quad * 8];

#pragma unroll
    for (int mi = 0; mi < 4; ++mi)
#pragma unroll
      for (int ni = 0; ni < 4; ++ni)
        acc[mi][ni] = __builtin_amdgcn_mfma_f32_16x16x32_bf16(
            af[mi], bfv[ni], acc[mi][ni], 0, 0, 0);
    __syncthreads();
  }

  // Epilogue. C/D layout (verified m89/m91): row m = quad*4+r, col n = lane&15.
#pragma unroll
  for (int mi = 0; mi < 4; ++mi) {
#pragma unroll
    for (int ni = 0; ni < 4; ++ni) {
      const int gn = bn0 + wn + ni * 16 + l15;
#pragma unroll
      for (int r = 0; r < 4; ++r) {
        const int gm = bm0 + wm + mi * 16 + quad * 4 + r;
        float v = acc[mi][ni][r];
        if (MODE == 0) {
          const int mat = gn >> 10;      // uniform per block (128 | 1024)
          const int d   = gn & 1023;
          const float* bias = (mat == 0) ? bq : (mat == 1) ? bk : bv;
          const __bf16 o = (__bf16)(v + bias[d]);
          if (mat == 0) {
            Qo[(size_t)gm * 1024 + d] = o;
          } else if (mat == 1) {
            Ko[(size_t)gm * 1024 + d] = o;
          } else {
            const int b = gm >> 11, s = gm & 2047;
            Vt[((size_t)b * 1024 + d) * 2048 + s] = o;  // V transposed [d][s]
          }
        } else {
          C[(long)blockIdx.z * sC + (size_t)gm * ldc + gn] = v;
        }
      }
    }
  }
}

// One block per row of 2048 fp32 scores. Applies 1/sqrt(D), softmax, writes
// bf16 weights IN-PLACE over the row (row stride stays 8192B = 4096 bf16).
__global__ __launch_bounds__(256)
void softmax_rows(float* __restrict__ S) {
  float* row = S + (size_t)blockIdx.x * 2048;
  __bf16* wrow = (__bf16*)row;
  const int t = threadIdx.x;
  const int wave = t >> 6;
  const int lane = t & 63;
  __shared__ float redm[4];
  __shared__ float reds[4];

  float4 a = ((const float4*)row)[t];
  float4 b = ((const float4*)row)[t + 256];
  const float sc = 0.03125f;  // 1/sqrt(1024)
  float x0 = a.x * sc, x1 = a.y * sc, x2 = a.z * sc, x3 = a.w * sc;
  float x4 = b.x * sc, x5 = b.y * sc, x6 = b.z * sc, x7 = b.w * sc;

  float mx = fmaxf(fmaxf(fmaxf(x0, x1), fmaxf(x2, x3)),
                   fmaxf(fmaxf(x4, x5), fmaxf(x6, x7)));
#pragma unroll
  for (int off = 32; off > 0; off >>= 1)
    mx = fmaxf(mx, __shfl_down(mx, off));
  if (lane == 0) redm[wave] = mx;
  __syncthreads();
  mx = fmaxf(fmaxf(redm[0], redm[1]), fmaxf(redm[2], redm[3]));

  float e0 = __expf(x0 - mx), e1 = __expf(x1 - mx);
  float e2 = __expf(x2 - mx), e3 = __expf(x3 - mx);
  float e4 = __expf(x4 - mx), e5 = __expf(x5 - mx);
  float e6 = __expf(x6 - mx), e7 = __expf(x7 - mx);
  float s = ((e0 + e1) + (e2 + e3)) + ((e4 + e5) + (e6 + e7));
#pragma unroll
  for (int off = 32; off > 0; off >>= 1)
    s += __shfl_down(s, off);
  if (lane == 0) reds[wave] = s;
  __syncthreads();
  const float rinv = 1.0f / (((reds[0] + reds[1]) + (reds[2] + reds[3])));

  bf16x4 w0, w1;
  w0[0] = (__bf16)(e0 * rinv); w0[1] = (__bf16)(e1 * rinv);
  w0[2] = (__bf16)(e2 * rinv); w0[3] = (__bf16)(e3 * rinv);
  w1[0] = (__bf16)(e4 * rinv); w1[1] = (__bf16)(e5 * rinv);
  w1[2] = (__bf16)(e6 * rinv); w1[3] = (__bf16)(e7 * rinv);
  // all reads happened before the barriers above; in-place write is safe
  ((bf16x4*)wrow)[t] = w0;
  ((bf16x4*)wrow)[t + 256] = w1;
}

extern "C" void kernel_launch(void* const* d_in, const int* in_sizes, int n_in,
                              void* d_out, int out_size, void* d_ws, size_t ws_size,
                              hipStream_t stream) {
  const float* x  = (const float*)d_in[0];
  const float* Wq = (const float*)d_in[1];
  const float* bq = (const float*)d_in[2];
  const float* Wk = (const float*)d_in[3];
  const float* bk = (const float*)d_in[4];
  const float* Wv = (const float*)d_in[5];
  const float* bv = (const float*)d_in[6];
  float* out = (float*)d_out;

  // ws layout (112 MiB total):
  //  [0,16M)   Q   bf16 [8192][1024]
  //  [16,32M)  K   bf16 [8192][1024]
  //  [32,48M)  Vt  bf16 [4][1024][2048]
  //  [48,64M)  xb  bf16 (phase-1 only)
  //  [64,70M)  Wcat bf16 [3072][1024] (phase-1 only)
  //  [48,112M) scores fp32 [4][2048][2048]  (aliases xb/Wcat, written later)
  char* ws = (char*)d_ws;
  __bf16* Q    = (__bf16*)(ws);
  __bf16* Kb   = (__bf16*)(ws + (16ull << 20));
  __bf16* Vt   = (__bf16*)(ws + (32ull << 20));
  __bf16* xb   = (__bf16*)(ws + (48ull << 20));
  __bf16* Wcat = (__bf16*)(ws + (64ull << 20));
  float*  Sc   = (float*)(ws + (48ull << 20));

  // fp32 -> bf16
  cvt_f32_bf16<<<8192, 256, 0, stream>>>(x, xb, 8388608 / 4);
  cvt_f32_bf16<<<1024, 256, 0, stream>>>(Wq, Wcat,                1048576 / 4);
  cvt_f32_bf16<<<1024, 256, 0, stream>>>(Wk, Wcat + 1048576,      1048576 / 4);
  cvt_f32_bf16<<<1024, 256, 0, stream>>>(Wv, Wcat + 2097152,      1048576 / 4);

  dim3 blk(256);
  // QKV: [8192,1024] @ [3072,1024]^T -> Q/K/Vt (bf16, +bias)
  gemm_bt<0><<<dim3(64, 24, 1), blk, 0, stream>>>(
      xb, Wcat, nullptr, 1024, 1024, 0, 1024,
      0L, 0L, 0L, bq, bk, bv, Q, Kb, Vt);

  // scores: per batch [2048,1024] @ [2048,1024]^T -> fp32 [2048,2048]
  gemm_bt<1><<<dim3(16, 16, 4), blk, 0, stream>>>(
      Q, Kb, Sc, 1024, 1024, 2048, 1024,
      2048L * 1024, 2048L * 1024, 2048L * 2048,
      nullptr, nullptr, nullptr, nullptr, nullptr, nullptr);

  softmax_rows<<<8192, 256, 0, stream>>>(Sc);

  // PV: per batch weights(bf16, lda=4096) [2048,2048] @ Vt[1024,2048]^T -> out fp32
  gemm_bt<1><<<dim3(16, 8, 4), blk, 0, stream>>>(
      (const __bf16*)Sc, Vt, out, 4096, 2048, 1024, 2048,
      2048L * 4096, 1024L * 2048, 2048L * 1024,
      nullptr, nullptr, nullptr, nullptr, nullptr, nullptr);
}

// Round 2
// 283.032 us; speedup vs baseline: 1.0134x; 1.0134x over previous
//
#include <hip/hip_runtime.h>

typedef __bf16 bf16x8 __attribute__((ext_vector_type(8)));
typedef __bf16 bf16x4 __attribute__((ext_vector_type(4)));
typedef float  f32x4  __attribute__((ext_vector_type(4)));

#define BM 128
#define BN 128
#define BK 32

// async global->LDS, 16B per lane. LDS dest must be wave-uniform base + lane*16.
__device__ __forceinline__ void gload_lds16(const __bf16* g, __bf16* l) {
  __builtin_amdgcn_global_load_lds(
      (const __attribute__((address_space(1))) void*)g,
      (__attribute__((address_space(3))) void*)l,
      16, 0, 0);
}

__global__ void cvt_f32_bf16(const float* __restrict__ s, __bf16* __restrict__ d, int n4) {
  int i = blockIdx.x * 256 + threadIdx.x;
  if (i < n4) {
    float4 v = ((const float4*)s)[i];
    bf16x4 o;
    o[0] = (__bf16)v.x; o[1] = (__bf16)v.y; o[2] = (__bf16)v.z; o[3] = (__bf16)v.w;
    ((bf16x4*)d)[i] = o;
  }
}

// All three weight matrices in one launch: Wq,Wk -> Wqk (concat), Wv -> Wvb.
__global__ void cvt_weights(const float* __restrict__ Wq, const float* __restrict__ Wk,
                            const float* __restrict__ Wv,
                            __bf16* __restrict__ Wqk, __bf16* __restrict__ Wvb) {
  const int mat = blockIdx.x >> 10;               // 1024 blocks per matrix
  const int i = (blockIdx.x & 1023) * 256 + threadIdx.x;  // float4 index, 262144/mat
  const float* src = (mat == 0) ? Wq : (mat == 1) ? Wk : Wv;
  __bf16* dst = (mat == 0) ? Wqk : (mat == 1) ? (Wqk + 1048576) : Wvb;
  float4 v = ((const float4*)src)[i];
  bf16x4 o;
  o[0] = (__bf16)v.x; o[1] = (__bf16)v.y; o[2] = (__bf16)v.z; o[3] = (__bf16)v.w;
  ((bf16x4*)dst)[i] = o;
}

// C[m,n] = sum_k A[m,k]*B[n,k]  (both K-contiguous). 128x128 tile, BK=32,
// 4 waves each computing 64x64 via 4x4 mfma_f32_16x16x32_bf16.
// MODE 0: QK epilogue  — bias + bf16 store, split by gn>>10 to Q / K row-major
// MODE 1: VT epilogue  — bias0[gm] + bf16 store to Vt[b][gm][s], gn = b*2048+s
// MODE 2: plain fp32 C store with ldc + batch stride (scores, PV)
template<int MODE>
__global__ __launch_bounds__(256, 2)
void gemm_bt(const __bf16* __restrict__ A, const __bf16* __restrict__ B,
             float* __restrict__ C,
             int lda, int ldb, int ldc, int K,
             long sA, long sB, long sC,
             const float* __restrict__ bias0, const float* __restrict__ bias1,
             __bf16* __restrict__ out0, __bf16* __restrict__ out1)
{
  A += (long)blockIdx.z * sA;
  B += (long)blockIdx.z * sB;

  const int tid  = threadIdx.x;
  const int wave = tid >> 6;
  const int lane = tid & 63;
  const int quad = lane >> 4;
  const int l15  = lane & 15;
  const int bm0  = blockIdx.x * BM;
  const int bn0  = blockIdx.y * BN;
  const int wm   = (wave >> 1) * 64;
  const int wn   = (wave & 1) * 64;

  __shared__ __align__(16) __bf16 As[BM * BK];
  __shared__ __align__(16) __bf16 Bs[BN * BK];

  f32x4 acc[4][4];
#pragma unroll
  for (int i = 0; i < 4; ++i)
#pragma unroll
    for (int j = 0; j < 4; ++j)
      acc[i][j] = (f32x4){0.f, 0.f, 0.f, 0.f};

  // staging: 128x32 bf16 = 8KB per tile; 256 threads x 16B x 2 chunks
  const int l0 = tid * 8;          // chunk 0 linear element
  const int l1 = (256 + tid) * 8;  // chunk 1
  const int r0 = l0 >> 5, c0 = l0 & 31;
  const int r1 = l1 >> 5, c1 = l1 & 31;
  const __bf16* Ag0 = A + (size_t)(bm0 + r0) * lda + c0;
  const __bf16* Ag1 = A + (size_t)(bm0 + r1) * lda + c1;
  const __bf16* Bg0 = B + (size_t)(bn0 + r0) * ldb + c0;
  const __bf16* Bg1 = B + (size_t)(bn0 + r1) * ldb + c1;

  for (int k0 = 0; k0 < K; k0 += BK) {
    gload_lds16(Ag0 + k0, &As[l0]);
    gload_lds16(Ag1 + k0, &As[l1]);
    gload_lds16(Bg0 + k0, &Bs[l0]);
    gload_lds16(Bg1 + k0, &Bs[l1]);
    __syncthreads();  // waits vmcnt(0) for the LDS-bound loads

    bf16x8 af[4], bfv[4];
#pragma unroll
    for (int i = 0; i < 4; ++i)
      af[i] = *(const bf16x8*)&As[(wm + i * 16 + l15) * BK + quad * 8];
#pragma unroll
    for (int i = 0; i < 4; ++i)
      bfv[i] = *(const bf16x8*)&Bs[(wn + i * 16 + l15) * BK + quad * 8];

#pragma unroll
    for (int mi = 0; mi < 4; ++mi)
#pragma unroll
      for (int ni = 0; ni < 4; ++ni)
        acc[mi][ni] = __builtin_amdgcn_mfma_f32_16x16x32_bf16(
            af[mi], bfv[ni], acc[mi][ni], 0, 0, 0);
    __syncthreads();
  }

  // Epilogue. C/D layout (verified m89/m91): row m = quad*4+r, col n = lane&15.
#pragma unroll
  for (int mi = 0; mi < 4; ++mi) {
#pragma unroll
    for (int ni = 0; ni < 4; ++ni) {
      const int gn = bn0 + wn + ni * 16 + l15;
#pragma unroll
      for (int r = 0; r < 4; ++r) {
        const int gm = bm0 + wm + mi * 16 + quad * 4 + r;
        float v = acc[mi][ni][r];
        if (MODE == 0) {
          // QK: gn in [0,2048); mat uniform per block (BN=128 divides 1024)
          const int mat = gn >> 10;
          const int d   = gn & 1023;
          const float* bias = (mat == 0) ? bias0 : bias1;
          __bf16* dst = (mat == 0) ? out0 : out1;
          dst[(size_t)gm * 1024 + d] = (__bf16)(v + bias[d]);
        } else if (MODE == 1) {
          // VT: gm = d in [0,1024), gn = b*2048 + s; store Vt[b][d][s]
          const int b = gn >> 11, s = gn & 2047;
          out0[(size_t)b * (1024 * 2048) + (size_t)gm * 2048 + s] =
              (__bf16)(v + bias0[gm]);
        } else {
          C[(long)blockIdx.z * sC + (size_t)gm * ldc + gn] = v;
        }
      }
    }
  }
}

// One block per row of 2048 fp32 scores. Applies 1/sqrt(D), softmax, writes
// bf16 weights IN-PLACE over the row (row stride stays 8192B = 4096 bf16).
__global__ __launch_bounds__(256)
void softmax_rows(float* __restrict__ S) {
  float* row = S + (size_t)blockIdx.x * 2048;
  __bf16* wrow = (__bf16*)row;
  const int t = threadIdx.x;
  const int wave = t >> 6;
  const int lane = t & 63;
  __shared__ float redm[4];
  __shared__ float reds[4];

  float4 a = ((const float4*)row)[t];
  float4 b = ((const float4*)row)[t + 256];
  const float sc = 0.03125f;  // 1/sqrt(1024)
  float x0 = a.x * sc, x1 = a.y * sc, x2 = a.z * sc, x3 = a.w * sc;
  float x4 = b.x * sc, x5 = b.y * sc, x6 = b.z * sc, x7 = b.w * sc;

  float mx = fmaxf(fmaxf(fmaxf(x0, x1), fmaxf(x2, x3)),
                   fmaxf(fmaxf(x4, x5), fmaxf(x6, x7)));
#pragma unroll
  for (int off = 32; off > 0; off >>= 1)
    mx = fmaxf(mx, __shfl_down(mx, off));
  if (lane == 0) redm[wave] = mx;
  __syncthreads();
  mx = fmaxf(fmaxf(redm[0], redm[1]), fmaxf(redm[2], redm[3]));

  float e0 = __expf(x0 - mx), e1 = __expf(x1 - mx);
  float e2 = __expf(x2 - mx), e3 = __expf(x3 - mx);
  float e4 = __expf(x4 - mx), e5 = __expf(x5 - mx);
  float e6 = __expf(x6 - mx), e7 = __expf(x7 - mx);
  float s = ((e0 + e1) + (e2 + e3)) + ((e4 + e5) + (e6 + e7));
#pragma unroll
  for (int off = 32; off > 0; off >>= 1)
    s += __shfl_down(s, off);
  if (lane == 0) reds[wave] = s;
  __syncthreads();
  const float rinv = 1.0f / (((reds[0] + reds[1]) + (reds[2] + reds[3])));

  bf16x4 w0, w1;
  w0[0] = (__bf16)(e0 * rinv); w0[1] = (__bf16)(e1 * rinv);
  w0[2] = (__bf16)(e2 * rinv); w0[3] = (__bf16)(e3 * rinv);
  w1[0] = (__bf16)(e4 * rinv); w1[1] = (__bf16)(e5 * rinv);
  w1[2] = (__bf16)(e6 * rinv); w1[3] = (__bf16)(e7 * rinv);
  // all reads happened before the barriers above; in-place write is safe
  ((bf16x4*)wrow)[t] = w0;
  ((bf16x4*)wrow)[t + 256] = w1;
}

extern "C" void kernel_launch(void* const* d_in, const int* in_sizes, int n_in,
                              void* d_out, int out_size, void* d_ws, size_t ws_size,
                              hipStream_t stream) {
  const float* x  = (const float*)d_in[0];
  const float* Wq = (const float*)d_in[1];
  const float* bq = (const float*)d_in[2];
  const float* Wk = (const float*)d_in[3];
  const float* bk = (const float*)d_in[4];
  const float* Wv = (const float*)d_in[5];
  const float* bv = (const float*)d_in[6];
  float* out = (float*)d_out;

  // ws layout (112 MiB total):
  //  [0,16M)   Q    bf16 [8192][1024]
  //  [16,32M)  K    bf16 [8192][1024]
  //  [32,48M)  Vt   bf16 [4][1024][2048]
  //  [48,64M)  xb   bf16 (projection phase only)
  //  [64,68M)  Wqk  bf16 [2048][1024] (projection phase only)
  //  [68,70M)  Wvb  bf16 [1024][1024] (projection phase only)
  //  [48,112M) scores fp32 [4][2048][2048]  (aliases xb/Wqk/Wvb, written later)
  char* ws = (char*)d_ws;
  __bf16* Q    = (__bf16*)(ws);
  __bf16* Kb   = (__bf16*)(ws + (16ull << 20));
  __bf16* Vt   = (__bf16*)(ws + (32ull << 20));
  __bf16* xb   = (__bf16*)(ws + (48ull << 20));
  __bf16* Wqk  = (__bf16*)(ws + (64ull << 20));
  __bf16* Wvb  = (__bf16*)(ws + (68ull << 20));
  float*  Sc   = (float*)(ws + (48ull << 20));

  // fp32 -> bf16
  cvt_f32_bf16<<<8192, 256, 0, stream>>>(x, xb, 8388608 / 4);
  cvt_weights<<<3072, 256, 0, stream>>>(Wq, Wk, Wv, Wqk, Wvb);

  dim3 blk(256);
  // QK: [8192,1024] @ [2048,1024]^T -> Q, K (bf16, +bias)
  gemm_bt<0><<<dim3(64, 16, 1), blk, 0, stream>>>(
      xb, Wqk, nullptr, 1024, 1024, 0, 1024,
      0L, 0L, 0L, bq, bk, Q, Kb);

  // VT: Wv[1024,1024] @ xb[8192,1024]^T -> Vt[b][d][s] (bf16, +bias[d])
  gemm_bt<1><<<dim3(8, 64, 1), blk, 0, stream>>>(
      Wvb, xb, nullptr, 1024, 1024, 0, 1024,
      0L, 0L, 0L, bv, nullptr, Vt, nullptr);

  // scores: per batch Q[2048,1024] @ K[2048,1024]^T -> fp32 [2048,2048]
  gemm_bt<2><<<dim3(16, 16, 4), blk, 0, stream>>>(
      Q, Kb, Sc, 1024, 1024, 2048, 1024,
      2048L * 1024, 2048L * 1024, 2048L * 2048,
      nullptr, nullptr, nullptr, nullptr);

  softmax_rows<<<8192, 256, 0, stream>>>(Sc);

  // PV: per batch weights(bf16, lda=4096) [2048,2048] @ Vt[1024,2048]^T -> out fp32
  gemm_bt<2><<<dim3(16, 8, 4), blk, 0, stream>>>(
      (const __bf16*)Sc, Vt, out, 4096, 2048, 1024, 2048,
      2048L * 4096, 1024L * 2048, 2048L * 1024,
      nullptr, nullptr, nullptr, nullptr);
}